// Round 5
// baseline (68.451 us; speedup 1.0000x reference)
//
#include <hip/hip_runtime.h>
#include <hip/hip_bf16.h>

// ContrastiveLoss: loss = ( sum_{same & sim<1} (1-sim) + sum_{diff & sim>0.5} sim ) / n
// sim = E E^T, n=8192, d=512. bf16 MFMA GEMM fused with mask/sum epilogue.
// R5: fix the LDS-BW bound. Wave tile 64x32 -> 64x64 (acc[4][4]) doubles
// FLOP per LDS byte (21.3 -> 32). 256-thr blocks, 4 waves 2x2, block tile
// 128^2, 3-buffer LDS + counted vmcnt(4) (never 0 in loop), 1 barrier/iter,
// T1 XCD swizzle, triangular grid. Swizzled staging kept from R4.

typedef __bf16 bf16x8 __attribute__((ext_vector_type(8)));
typedef __bf16 bf16x4 __attribute__((ext_vector_type(4)));
typedef float  f32x4  __attribute__((ext_vector_type(4)));

#define N_EMB 8192
#define D_EMB 512
#define BM    128
#define BK    32
#define KT    (D_EMB / BK)      // 16
#define TILES (N_EMB / BM)      // 64
#define NBLK  (TILES * (TILES + 1) / 2)   // 2080
#define MARGIN_F 0.5f
#define OPER  (BM * BK)         // 4096 elems per operand tile (8 KB)

__device__ __forceinline__ void gll16(const __bf16* g, __bf16* l) {
    __builtin_amdgcn_global_load_lds(
        (const __attribute__((address_space(1))) void*)g,
        (__attribute__((address_space(3))) void*)l,
        16 /*bytes*/, 0 /*offset*/, 0 /*aux*/);
}

__global__ __launch_bounds__(256) void cvt_kernel(const float* __restrict__ in,
                                                  __bf16* __restrict__ out, int n4) {
    int i = blockIdx.x * blockDim.x + threadIdx.x;
    if (i < n4) {
        float4 v = reinterpret_cast<const float4*>(in)[i];
        bf16x4 o;
        o.x = (__bf16)v.x; o.y = (__bf16)v.y; o.z = (__bf16)v.z; o.w = (__bf16)v.w;
        reinterpret_cast<bf16x4*>(out)[i] = o;
    }
}

__global__ __launch_bounds__(256, 3) void loss_kernel(const __bf16* __restrict__ E,
                                                      const int* __restrict__ label,
                                                      float* __restrict__ partials) {
    // T1: XCD-contiguous logical tile index (2080 % 8 == 0)
    const int bid = blockIdx.x;
    const int t = (bid & 7) * (NBLK / 8) + (bid >> 3);

    // triangular decode: t -> (tr, tc), tr <= tc (verified R2/R4)
    int tr = (int)(64.5f - sqrtf(4160.25f - 2.0f * (float)t));
    while ((tr + 1) * TILES - ((tr + 1) * tr) / 2 <= t) ++tr;
    while (tr * TILES - (tr * (tr - 1)) / 2 > t) --tr;
    const int tc = tr + (t - (tr * TILES - (tr * (tr - 1)) / 2));

    __shared__ __bf16 lds[3][2 * OPER];   // 3 x 16 KB (A tile then B tile)
    __shared__ float  red[4];

    const int tid  = threadIdx.x;
    const int wid  = tid >> 6, lane = tid & 63;
    const int wrow = wid >> 1, wcol = wid & 1;   // 2x2 waves, each 64x64 out
    const int fr   = lane & 15;                  // fragment row(A)/row(B)/col(C)
    const int kq   = lane >> 4;                  // logical k-octet 0..3
    const int row0 = tr * BM, col0 = tc * BM;

    // ---- staging map: 16B slot s (0..511 per operand): row = s>>2, phys
    // slot = s&3 holding LOGICAL slot (s&3)^(row&3)  (linear LDS dest,
    // inverse-swizzled global source). Thread t covers s = t and s = t+256.
    const int r0s = tid >> 2;                    // rows 0..63
    const int r1s = 64 + r0s;                    // rows 64..127
    const int l0  = (((tid & 3) ^ (r0s & 3)) << 3);
    const int l1  = (((tid & 3) ^ (r1s & 3)) << 3);
    const __bf16* gA0 = E + (size_t)(row0 + r0s) * D_EMB + l0;
    const __bf16* gA1 = E + (size_t)(row0 + r1s) * D_EMB + l1;
    const __bf16* gB0 = E + (size_t)(col0 + r0s) * D_EMB + l0;
    const __bf16* gB1 = E + (size_t)(col0 + r1s) * D_EMB + l1;
    const int d0 = tid << 3;                     // elem offset of slot t
    const int d1 = (tid + 256) << 3;             // elem offset of slot t+256

    f32x4 acc[4][4] = {};

    // swizzled ds_read offset within a row (row&3 == fr&3 for all frag rows)
    const int ps = ((kq ^ (fr & 3)) << 3);

    // prologue: stage tiles 0 and 1 (8 glls outstanding per wave)
    {
        __bf16* L0 = lds[0]; __bf16* L1 = lds[1];
        gll16(gA0,      L0 + d0);        gll16(gA1,      L0 + d1);
        gll16(gB0,      L0 + OPER + d0); gll16(gB1,      L0 + OPER + d1);
        gll16(gA0 + BK, L1 + d0);        gll16(gA1 + BK, L1 + d1);
        gll16(gB0 + BK, L1 + OPER + d0); gll16(gB1 + BK, L1 + OPER + d1);
    }

    __bf16* rd  = lds[0];   // tile kt
    __bf16* pre = lds[1];   // tile kt+1
    __bf16* wr  = lds[2];   // tile kt+2 destination

#pragma unroll 1
    for (int kt = 0; kt < KT - 1; ++kt) {
        // tile kt's 4 glls done; kt+1's 4 still in flight (never vmcnt(0))
        asm volatile("s_waitcnt vmcnt(4)" ::: "memory");
        __builtin_amdgcn_s_barrier();   // kt visible to all; 'wr' free

        if (kt + 2 < KT) {
            const int k2 = (kt + 2) * BK;
            gll16(gA0 + k2, wr + d0);        gll16(gA1 + k2, wr + d1);
            gll16(gB0 + k2, wr + OPER + d0); gll16(gB1 + k2, wr + OPER + d1);
        }
        __builtin_amdgcn_sched_barrier(0);   // keep stage-issue ahead of compute

        bf16x8 a[4], b[4];
#pragma unroll
        for (int m = 0; m < 4; ++m)
            a[m] = *reinterpret_cast<const bf16x8*>(&rd[(wrow * 64 + m * 16 + fr) * BK + ps]);
#pragma unroll
        for (int n = 0; n < 4; ++n)
            b[n] = *reinterpret_cast<const bf16x8*>(&rd[OPER + (wcol * 64 + n * 16 + fr) * BK + ps]);
#pragma unroll
        for (int m = 0; m < 4; ++m)
#pragma unroll
            for (int n = 0; n < 4; ++n)
                acc[m][n] = __builtin_amdgcn_mfma_f32_16x16x32_bf16(a[m], b[n], acc[m][n], 0, 0, 0);

        __bf16* tmp = rd; rd = pre; pre = wr; wr = tmp;   // rotate buffers
    }

    // last tile: drain
    asm volatile("s_waitcnt vmcnt(0)" ::: "memory");
    __builtin_amdgcn_s_barrier();
    {
        bf16x8 a[4], b[4];
#pragma unroll
        for (int m = 0; m < 4; ++m)
            a[m] = *reinterpret_cast<const bf16x8*>(&rd[(wrow * 64 + m * 16 + fr) * BK + ps]);
#pragma unroll
        for (int n = 0; n < 4; ++n)
            b[n] = *reinterpret_cast<const bf16x8*>(&rd[OPER + (wcol * 64 + n * 16 + fr) * BK + ps]);
#pragma unroll
        for (int m = 0; m < 4; ++m)
#pragma unroll
            for (int n = 0; n < 4; ++n)
                acc[m][n] = __builtin_amdgcn_mfma_f32_16x16x32_bf16(a[m], b[n], acc[m][n], 0, 0, 0);
    }

    // ---- epilogue: C/D layout col = lane&15, row = (lane>>4)*4 + reg [m89]
    float local = 0.f;
    int lj[4];
#pragma unroll
    for (int n = 0; n < 4; ++n) lj[n] = label[col0 + wcol * 64 + n * 16 + fr];
    const int rb = kq << 2;
#pragma unroll
    for (int m = 0; m < 4; ++m) {
#pragma unroll
        for (int r = 0; r < 4; ++r) {
            const int li = label[row0 + wrow * 64 + m * 16 + rb + r];
#pragma unroll
            for (int n = 0; n < 4; ++n) {
                const float s = acc[m][n][r];
                if (li == lj[n]) {
                    if (s < 1.0f) local += 1.0f - s;
                } else if (s > MARGIN_F) {
                    local += s;
                }
            }
        }
    }
    if (tr != tc) local *= 2.0f;   // off-diag tile stands for (i,j) and (j,i)

#pragma unroll
    for (int off = 32; off > 0; off >>= 1) local += __shfl_xor(local, off);
    if (lane == 0) red[wid] = local;
    __syncthreads();
    if (tid == 0) partials[t] = red[0] + red[1] + red[2] + red[3];
}

__global__ __launch_bounds__(256) void reduce_kernel(const float* __restrict__ partials,
                                                     float* __restrict__ out, int nb) {
    float s = 0.f;
    for (int i = threadIdx.x; i < nb; i += 256) s += partials[i];
#pragma unroll
    for (int off = 32; off > 0; off >>= 1) s += __shfl_xor(s, off);
    __shared__ float red[4];
    if ((threadIdx.x & 63) == 0) red[threadIdx.x >> 6] = s;
    __syncthreads();
    if (threadIdx.x == 0) {
        out[0] = (red[0] + red[1] + red[2] + red[3]) * (1.0f / (float)N_EMB);
        out[1] = 0.f;
        out[2] = 0.f;
    }
}

extern "C" void kernel_launch(void* const* d_in, const int* in_sizes, int n_in,
                              void* d_out, int out_size, void* d_ws, size_t ws_size,
                              hipStream_t stream) {
    const float* emb   = (const float*)d_in[0];
    const int*   label = (const int*)d_in[1];
    float*       out   = (float*)d_out;

    __bf16* Ebf     = (__bf16*)d_ws;                                     // 8 MB
    float*  partial = (float*)((char*)d_ws + (size_t)N_EMB * D_EMB * 2); // 8.3 KB

    const int n4 = N_EMB * D_EMB / 4;
    cvt_kernel<<<(n4 + 255) / 256, 256, 0, stream>>>(emb, Ebf, n4);

    loss_kernel<<<NBLK, 256, 0, stream>>>(Ebf, label, partial);

    reduce_kernel<<<1, 256, 0, stream>>>(partial, out, NBLK);
}